// Round 12
// baseline (190.015 us; speedup 1.0000x reference)
//
#include <hip/hip_runtime.h>
#include <math.h>

// L2ClusterCentroid: N=1e6 rows, D=128, C=100.
// assign = argmax(logits, -1); centroids = segment_mean(embedding, assign);
// out[c] = counts[c]>0 ? ||centers[c] - centroids[c]||_2 : 0
//
// Round-12: K1 was 15625 one-shot blocks -> ~40% of each wave's lifetime was
// kernarg-preamble (predicted 0.6*6.7 = 4.3 TB/s; measured 4.4). Now K1 is
// persistent: 1024 blocks x ~15 row-groups, A/B ping-pong prefetch with
// sched_barrier(0) fences so prefetch loads stay above the argmax VALU.
// K2 (queued gather, 16B/lane drains) and K3 unchanged from round 11.

#define NROWS 1000000
#define DIM   128
#define NCLS  100
#define NSLICE 16
#define SLICE_ROWS (NROWS / NSLICE)   // 62500
#define PSTRIDE 132                   // 128 dims + count + pad (528 B, 16B-aligned)
#define QCAP  128
#define QMASK 127
#define GROUPS (NROWS / 64)           // 15625 row-groups of 64
#define K1_BLOCKS 1024

typedef __attribute__((ext_vector_type(4))) float f32x4;

// ---------------- K1: persistent argmax over logits rows ----------------
__device__ __forceinline__ void k1_load(const float* __restrict__ logits,
                                        int grp, int g, int p,
                                        f32x4 v[6], float& t)
{
    const float* lr = logits + (size_t)(grp * 64 + g) * NCLS;
    #pragma unroll
    for (int i = 0; i < 6; ++i)
        v[i] = *reinterpret_cast<const f32x4*>(lr + i * 16 + p * 4);
    t = lr[96 + p];
}

__device__ __forceinline__ void k1_process(const f32x4 v[6], float t,
                                           int grp, int g, int p,
                                           int* __restrict__ assign)
{
    float best = -INFINITY;
    int   bi   = 0x7fffffff;
    #pragma unroll
    for (int i = 0; i < 6; ++i) {
        const int c0 = i * 16 + p * 4;
        if (v[i][0] > best) { best = v[i][0]; bi = c0;     }
        if (v[i][1] > best) { best = v[i][1]; bi = c0 + 1; }
        if (v[i][2] > best) { best = v[i][2]; bi = c0 + 2; }
        if (v[i][3] > best) { best = v[i][3]; bi = c0 + 3; }
    }
    if (t > best) { best = t; bi = 96 + p; }
    #pragma unroll
    for (int off = 1; off <= 2; off <<= 1) {    // quad_perm DPP merge
        const float ov = __shfl_xor(best, off, 64);
        const int   oi = __shfl_xor(bi,   off, 64);
        if (ov > best || (ov == best && oi < bi)) { best = ov; bi = oi; }
    }
    if (p == 0) assign[grp * 64 + g] = bi;
}

__global__ __launch_bounds__(256)
void l2cc_argmax(const float* __restrict__ logits, int* __restrict__ assign)
{
    const int g = threadIdx.x >> 2;   // quad id 0..63 -> row within group
    const int p = threadIdx.x & 3;
    const int stride = gridDim.x;

    int grp = blockIdx.x;
    if (grp >= GROUPS) return;

    f32x4 vA[6], vB[6];
    float tA, tB;

    k1_load(logits, grp, g, p, vA, tA);
    for (;;) {
        const int g1 = grp + stride;
        if (g1 < GROUPS) k1_load(logits, g1, g, p, vB, tB);
        __builtin_amdgcn_sched_barrier(0);      // keep prefetch above VALU
        k1_process(vA, tA, grp, g, p, assign);
        if (g1 >= GROUPS) break;

        const int g2 = g1 + stride;
        if (g2 < GROUPS) k1_load(logits, g2, g, p, vA, tA);
        __builtin_amdgcn_sched_barrier(0);
        k1_process(vB, tB, g1, g, p, assign);
        if (g2 >= GROUPS) break;
        grp = g2;
    }
}

// ---------------- K2: scan + queued batch-gather (16B/lane drains) ----------------
// Drain 16 queued rows as 8 wave-instructions: lanes 0-31 take row 2k,
// lanes 32-63 take row 2k+1; each lane loads f32x4 = dims l5*4..+3.
#define DRAIN16                                                               \
    {                                                                         \
        _Pragma("unroll")                                                     \
        for (int k_ = 0; k_ < 8; ++k_) {                                      \
            const int r_ = q[wave][(qhead + 2 * k_ + half) & QMASK];          \
            acc += *reinterpret_cast<const f32x4*>(                           \
                emb + (size_t)r_ * DIM + l5 * 4);                             \
        }                                                                     \
        qhead += 16;                                                          \
    }

#define PUSH(AV, OFF)                                                         \
    {                                                                         \
        const unsigned long long m_ = __ballot((AV) == c);                    \
        if ((AV) == c) {                                                      \
            const int rank_ = __popcll(m_ & ((1ull << lane) - 1ull));         \
            q[wave][(qtail + rank_) & QMASK] = rw + (OFF) + lane;             \
        }                                                                     \
        const int pc_ = __popcll(m_);                                         \
        qtail += pc_; icnt += pc_;                                            \
        while (qtail - qhead >= 16) DRAIN16                                   \
    }

__global__ __launch_bounds__(256)
void l2cc_gather(const float* __restrict__ emb,
                 const int* __restrict__ assign,
                 float* __restrict__ partial)
{
    const int bid  = blockIdx.x;
    const int c    = bid / NSLICE;       // cluster this block owns
    const int sl   = bid - c * NSLICE;   // row-slice
    const int wave = threadIdx.x >> 6;
    const int lane = threadIdx.x & 63;
    const int half = lane >> 5;          // 0: even queue slot, 1: odd
    const int l5   = lane & 31;          // dim-quad index within row

    __shared__ int   q[4][QCAP];         // per-wave matched-row-id ring
    __shared__ f32x4 sacc[4][64];        // per-wave per-lane dim sums (4 KB)
    __shared__ int   scnt[4];

    const int start = sl * SLICE_ROWS;
    const int end   = start + SLICE_ROWS;

    f32x4 acc = {0.0f, 0.0f, 0.0f, 0.0f};
    int   icnt = 0, qhead = 0, qtail = 0;

    int rw = start + wave * 256;
    int a0 = (rw +   0 + lane < end) ? assign[rw +   0 + lane] : -1;
    int a1 = (rw +  64 + lane < end) ? assign[rw +  64 + lane] : -1;
    int a2 = (rw + 128 + lane < end) ? assign[rw + 128 + lane] : -1;
    int a3 = (rw + 192 + lane < end) ? assign[rw + 192 + lane] : -1;

    for (; rw < end; rw += 1024) {
        const int rn = rw + 1024;        // prefetch next 256-row group
        int b0 = -1, b1 = -1, b2 = -1, b3 = -1;
        if (rn < end) {
            b0 = (rn +   0 + lane < end) ? assign[rn +   0 + lane] : -1;
            b1 = (rn +  64 + lane < end) ? assign[rn +  64 + lane] : -1;
            b2 = (rn + 128 + lane < end) ? assign[rn + 128 + lane] : -1;
            b3 = (rn + 192 + lane < end) ? assign[rn + 192 + lane] : -1;
        }

        PUSH(a0, 0) PUSH(a1, 64) PUSH(a2, 128) PUSH(a3, 192)

        a0 = b0; a1 = b1; a2 = b2; a3 = b3;
    }

    // tail: remaining queued rows, one at a time (half-wave active)
    while (qtail > qhead) {
        const int r = q[wave][qhead & QMASK]; ++qhead;
        if (half == 0)
            acc += *reinterpret_cast<const f32x4*>(emb + (size_t)r * DIM + l5 * 4);
    }

    // cross-wave/half reduce (fixed order, deterministic)
    sacc[wave][lane] = acc;
    if (lane == 0) scnt[wave] = icnt;
    __syncthreads();
    if (wave == 0 && lane < 32) {
        f32x4 v = (((sacc[0][lane] + sacc[1][lane]) + sacc[2][lane]) + sacc[3][lane])
                + (((sacc[0][32 + lane] + sacc[1][32 + lane])
                  + sacc[2][32 + lane]) + sacc[3][32 + lane]);
        float* p = partial + (size_t)bid * PSTRIDE;
        *reinterpret_cast<f32x4*>(p + lane * 4) = v;       // dims 4l..4l+3 (linear)
        if (lane == 0)
            p[DIM] = (float)(((scnt[0] + scnt[1]) + scnt[2]) + scnt[3]);
    }
}

// ---------------- K3: per-cluster slice reduction + distance epilogue ----------------
__global__ __launch_bounds__(128)
void l2cc_final(const float* __restrict__ partial,
                const float* __restrict__ centers,
                float* __restrict__ out)
{
    const int c = blockIdx.x;     // 0..99
    const int t = threadIdx.x;    // 0..127 = dim (linear layout)

    float s = 0.0f, cnt = 0.0f;
    #pragma unroll
    for (int sl = 0; sl < NSLICE; ++sl) {
        const float* p = partial + (size_t)(c * NSLICE + sl) * PSTRIDE;
        s   += p[t];
        cnt += p[DIM];
    }

    const float centroid = s / fmaxf(cnt, 1.0f);
    const float dd = centers[c * DIM + t] - centroid;
    float sq = dd * dd;
    #pragma unroll
    for (int off = 32; off > 0; off >>= 1) sq += __shfl_xor(sq, off, 64);

    __shared__ float red[2];
    if ((t & 63) == 0) red[t >> 6] = sq;
    __syncthreads();
    if (t == 0) {
        const float total = red[0] + red[1];
        out[c] = (cnt > 0.0f && total > 0.0f) ? sqrtf(total) : 0.0f;
    }
}

extern "C" void kernel_launch(void* const* d_in, const int* in_sizes, int n_in,
                              void* d_out, int out_size, void* d_ws, size_t ws_size,
                              hipStream_t stream)
{
    const float* emb     = (const float*)d_in[0];  // [N, 128]
    const float* centers = (const float*)d_in[1];  // [100, 128]
    const float* logits  = (const float*)d_in[2];  // [N, 100]
    float* out = (float*)d_out;                    // [100]

    // workspace: assign [N ints, 4 MB] then partials [1600][132] f32 (~845 KB)
    int*   assign  = (int*)d_ws;
    float* partial = (float*)((char*)d_ws + (size_t)NROWS * sizeof(int));

    l2cc_argmax<<<K1_BLOCKS, 256, 0, stream>>>(logits, assign);
    l2cc_gather<<<NCLS * NSLICE, 256, 0, stream>>>(emb, assign, partial);
    l2cc_final <<<NCLS, 128, 0, stream>>>(partial, centers, out);
}